// Round 1
// baseline (828.320 us; speedup 1.0000x reference)
//
#include <hip/hip_runtime.h>

#define D_MODEL 2048
#define S_LEN 2048
#define NB 2
#define NH 16
#define DK 128

typedef __attribute__((ext_vector_type(8))) __bf16 bf16x8;
typedef __attribute__((ext_vector_type(4))) float f32x4;

__device__ __forceinline__ unsigned short f2bf(float f) {
    unsigned int u = __float_as_uint(f);
    return (unsigned short)((u + 0x7fffu + ((u >> 16) & 1u)) >> 16);
}

__global__ void cast_f32_to_bf16(const float* __restrict__ x,
                                 unsigned short* __restrict__ y, int n4) {
    int i = blockIdx.x * blockDim.x + threadIdx.x;
    int stride = gridDim.x * blockDim.x;
    const float4* x4 = (const float4*)x;
    ushort4* y4 = (ushort4*)y;
    for (; i < n4; i += stride) {
        float4 v = x4[i];
        ushort4 o;
        o.x = f2bf(v.x); o.y = f2bf(v.y); o.z = f2bf(v.z); o.w = f2bf(v.w);
        y4[i] = o;
    }
}

// ---------------- GEMM: C[m,n] = sum_k A[m,k] * Bt[n,k] ----------------
#define BM 128
#define BN 128
#define BK 32
#define LDS_STRIDE 40  // 32 + 8 pad (keeps 16B alignment, breaks bank stride)

__device__ __forceinline__ void cstore(float* p, float v) { *p = v; }
__device__ __forceinline__ void cstore(unsigned short* p, float v) { *p = f2bf(v); }

template <typename OutT>
__global__ __launch_bounds__(256) void gemm_bt(const unsigned short* __restrict__ A,
                                               const unsigned short* __restrict__ Bt,
                                               OutT* __restrict__ C,
                                               int M, int N, int K) {
    __shared__ __align__(16) unsigned short As[BM * LDS_STRIDE];
    __shared__ __align__(16) unsigned short Bs[BN * LDS_STRIDE];
    const int tid = threadIdx.x;
    const int lane = tid & 63;
    const int wave = tid >> 6;
    const int quad = lane >> 4;
    const int l15 = lane & 15;
    const int wr = (wave >> 1) * 64;
    const int wc = (wave & 1) * 64;
    const int m0 = blockIdx.x * BM;
    const int n0 = blockIdx.y * BN;

    f32x4 zero = {0.f, 0.f, 0.f, 0.f};
    f32x4 acc[4][4];
    for (int i = 0; i < 4; i++)
        for (int j = 0; j < 4; j++) acc[i][j] = zero;

    for (int k0 = 0; k0 < K; k0 += BK) {
        __syncthreads();
#pragma unroll
        for (int p = 0; p < 2; p++) {
            int flat = p * 256 + tid;       // 0..511 16B-chunks
            int row = flat >> 2;            // 0..127
            int kc = (flat & 3) * 8;        // 0,8,16,24
            uint4 av = *(const uint4*)(A + (size_t)(m0 + row) * K + k0 + kc);
            uint4 bv = *(const uint4*)(Bt + (size_t)(n0 + row) * K + k0 + kc);
            *(uint4*)(&As[row * LDS_STRIDE + kc]) = av;
            *(uint4*)(&Bs[row * LDS_STRIDE + kc]) = bv;
        }
        __syncthreads();
        bf16x8 af[4], bfr[4];
#pragma unroll
        for (int t = 0; t < 4; t++) {
            af[t]  = *(const bf16x8*)(&As[(wr + t * 16 + l15) * LDS_STRIDE + quad * 8]);
            bfr[t] = *(const bf16x8*)(&Bs[(wc + t * 16 + l15) * LDS_STRIDE + quad * 8]);
        }
#pragma unroll
        for (int mt = 0; mt < 4; mt++)
#pragma unroll
            for (int nt = 0; nt < 4; nt++)
                acc[mt][nt] = __builtin_amdgcn_mfma_f32_16x16x32_bf16(
                    af[mt], bfr[nt], acc[mt][nt], 0, 0, 0);
    }

#pragma unroll
    for (int mt = 0; mt < 4; mt++)
#pragma unroll
        for (int nt = 0; nt < 4; nt++)
#pragma unroll
            for (int r = 0; r < 4; r++) {
                int m = m0 + wr + mt * 16 + quad * 4 + r;
                int n = n0 + wc + nt * 16 + l15;
                cstore(&C[(size_t)m * N + n], acc[mt][nt][r]);
            }
}

// ---------------- Flash attention with softcap ----------------
#define KS_STRIDE 136  // 128 + 8
#define VT_STRIDE 72   // 64 + 8
#define PS_STRIDE 72   // 64 + 8

__global__ __launch_bounds__(256) void flash_attn(
        const unsigned short* __restrict__ Q,
        const unsigned short* __restrict__ K,
        const unsigned short* __restrict__ V,
        const float* __restrict__ bias,
        const int* __restrict__ softcap,
        unsigned short* __restrict__ O) {
    __shared__ __align__(16) unsigned short Ks[64 * KS_STRIDE];
    __shared__ __align__(16) unsigned short VT[128 * VT_STRIDE];
    __shared__ __align__(16) unsigned short Ps[4 * 16 * PS_STRIDE];

    const int tid = threadIdx.x;
    const int lane = tid & 63;
    const int wave = tid >> 6;
    const int quad = lane >> 4;
    const int l15 = lane & 15;
    const int sb = blockIdx.x;
    const int h = blockIdx.y;
    const int b = blockIdx.z;
    const int q0 = sb * 64;

    const float scale = 0.08838834764831845f;  // 1/sqrt(128)
    const float cap = (float)softcap[0];
    const float inv_cap = 1.0f / cap;

    const size_t head_off = (size_t)b * S_LEN * D_MODEL + (size_t)h * DK;

    // Q fragments: A-layout, 16 q-rows per wave, d = 0..127 in 4 chunks of 32
    bf16x8 qf[4];
    {
        const unsigned short* Qp = Q + head_off + (size_t)(q0 + wave * 16 + l15) * D_MODEL;
#pragma unroll
        for (int c = 0; c < 4; c++)
            qf[c] = *(const bf16x8*)(Qp + c * 32 + quad * 8);
    }

    f32x4 zero = {0.f, 0.f, 0.f, 0.f};
    float m_run[4], l_run[4];
    f32x4 o_acc[8];
#pragma unroll
    for (int r = 0; r < 4; r++) { m_run[r] = -1e30f; l_run[r] = 0.f; }
#pragma unroll
    for (int d = 0; d < 8; d++) o_acc[d] = zero;

    unsigned short* Psw = &Ps[wave * 16 * PS_STRIDE];

    for (int kt = 0; kt < S_LEN / 64; kt++) {
        const int kbase = kt * 64;
        __syncthreads();
        // stage K tile [64][128] and V tile transposed -> VT[d][kk]
#pragma unroll
        for (int p = 0; p < 4; p++) {
            int flat = p * 256 + tid;       // 0..1023 chunks of 8
            int row = flat >> 4;            // 0..63 (key row)
            int cc = (flat & 15) * 8;       // d offset 0..120
            uint4 kv = *(const uint4*)(K + head_off + (size_t)(kbase + row) * D_MODEL + cc);
            *(uint4*)(&Ks[row * KS_STRIDE + cc]) = kv;
            uint4 vv = *(const uint4*)(V + head_off + (size_t)(kbase + row) * D_MODEL + cc);
            union { uint4 u; unsigned short s[8]; } cv; cv.u = vv;
#pragma unroll
            for (int j = 0; j < 8; j++)
                VT[(cc + j) * VT_STRIDE + row] = cv.s[j];
        }
        __syncthreads();

        // scores: S = Q K^T  (16 x 64 per wave), accumulate over d chunks
        f32x4 s[4];
#pragma unroll
        for (int nt = 0; nt < 4; nt++) {
            s[nt] = zero;
#pragma unroll
            for (int c = 0; c < 4; c++) {
                bf16x8 kf = *(const bf16x8*)(&Ks[(nt * 16 + l15) * KS_STRIDE + c * 32 + quad * 8]);
                s[nt] = __builtin_amdgcn_mfma_f32_16x16x32_bf16(qf[c], kf, s[nt], 0, 0, 0);
            }
        }

        // scale + bias + softcap: x = cap * tanh((qk*scale + bias)/cap)
        const int qrow = q0 + wave * 16 + quad * 4;
#pragma unroll
        for (int nt = 0; nt < 4; nt++) {
            int kg = kbase + nt * 16 + l15;
#pragma unroll
            for (int r = 0; r < 4; r++) {
                float x = fmaf(s[nt][r], scale, bias[(size_t)(qrow + r) * S_LEN + kg]);
                float xa = fabsf(x * inv_cap);
                float e = __expf(-2.0f * xa);
                float t = (1.0f - e) / (1.0f + e);
                s[nt][r] = cap * copysignf(t, x);
            }
        }

        // online softmax (row stats live in C-layout: row = quad*4+r)
        float alpha[4];
#pragma unroll
        for (int r = 0; r < 4; r++) {
            float mx = fmaxf(fmaxf(s[0][r], s[1][r]), fmaxf(s[2][r], s[3][r]));
            mx = fmaxf(mx, __shfl_xor(mx, 1, 64));
            mx = fmaxf(mx, __shfl_xor(mx, 2, 64));
            mx = fmaxf(mx, __shfl_xor(mx, 4, 64));
            mx = fmaxf(mx, __shfl_xor(mx, 8, 64));
            float mnew = fmaxf(m_run[r], mx);
            alpha[r] = __expf(m_run[r] - mnew);
            m_run[r] = mnew;
            float acc_s = 0.f;
#pragma unroll
            for (int nt = 0; nt < 4; nt++) {
                float p = __expf(s[nt][r] - mnew);
                s[nt][r] = p;
                acc_s += p;
            }
            acc_s += __shfl_xor(acc_s, 1, 64);
            acc_s += __shfl_xor(acc_s, 2, 64);
            acc_s += __shfl_xor(acc_s, 4, 64);
            acc_s += __shfl_xor(acc_s, 8, 64);
            l_run[r] = l_run[r] * alpha[r] + acc_s;
        }
#pragma unroll
        for (int d = 0; d < 8; d++)
#pragma unroll
            for (int r = 0; r < 4; r++)
                o_acc[d][r] *= alpha[r];

        // P: C-layout -> LDS -> A-layout (per-wave region)
#pragma unroll
        for (int nt = 0; nt < 4; nt++)
#pragma unroll
            for (int r = 0; r < 4; r++)
                Psw[(quad * 4 + r) * PS_STRIDE + nt * 16 + l15] = f2bf(s[nt][r]);
        __syncthreads();

        // O += P V : A = P (16x64), B = V (64x128); k chunks of 32 -> c in {0,1}
#pragma unroll
        for (int c = 0; c < 2; c++) {
            bf16x8 pf = *(const bf16x8*)(&Psw[l15 * PS_STRIDE + c * 32 + quad * 8]);
#pragma unroll
            for (int d = 0; d < 8; d++) {
                bf16x8 vf = *(const bf16x8*)(&VT[(d * 16 + l15) * VT_STRIDE + c * 32 + quad * 8]);
                o_acc[d] = __builtin_amdgcn_mfma_f32_16x16x32_bf16(pf, vf, o_acc[d], 0, 0, 0);
            }
        }
    }

    // finalize: O / l, write bf16 [B*S, D_MODEL] at head column offset
#pragma unroll
    for (int r = 0; r < 4; r++) {
        float inv = 1.0f / l_run[r];
        int row = q0 + wave * 16 + quad * 4 + r;
        unsigned short* Op = O + (size_t)(b * S_LEN + row) * D_MODEL + h * DK;
#pragma unroll
        for (int d = 0; d < 8; d++)
            Op[d * 16 + l15] = f2bf(o_acc[d][r] * inv);
    }
}

// ---------------- host ----------------
extern "C" void kernel_launch(void* const* d_in, const int* in_sizes, int n_in,
                              void* d_out, int out_size, void* d_ws, size_t ws_size,
                              hipStream_t stream) {
    const float* inp = (const float*)d_in[0];
    const float* wq  = (const float*)d_in[1];
    const float* wk  = (const float*)d_in[2];
    const float* wv  = (const float*)d_in[3];
    const float* wo  = (const float*)d_in[4];
    const float* bias = (const float*)d_in[5];
    const int* softcap = (const int*)d_in[6];
    float* out = (float*)d_out;

    unsigned short* ws = (unsigned short*)d_ws;
    const size_t n_inp = (size_t)NB * S_LEN * D_MODEL;  // 8,388,608
    const size_t n_w = (size_t)D_MODEL * D_MODEL;       // 4,194,304
    unsigned short* inp_b = ws;
    unsigned short* wq_b = inp_b + n_inp;
    unsigned short* wk_b = wq_b + n_w;
    unsigned short* wv_b = wk_b + n_w;
    unsigned short* wo_b = wv_b + n_w;
    unsigned short* Qb = wo_b + n_w;
    unsigned short* Kb = Qb + n_inp;
    unsigned short* Vb = Kb + n_inp;
    unsigned short* Ob = Vb + n_inp;

    cast_f32_to_bf16<<<dim3(1024), dim3(256), 0, stream>>>(inp, inp_b, (int)(n_inp / 4));
    cast_f32_to_bf16<<<dim3(512), dim3(256), 0, stream>>>(wq, wq_b, (int)(n_w / 4));
    cast_f32_to_bf16<<<dim3(512), dim3(256), 0, stream>>>(wk, wk_b, (int)(n_w / 4));
    cast_f32_to_bf16<<<dim3(512), dim3(256), 0, stream>>>(wv, wv_b, (int)(n_w / 4));
    cast_f32_to_bf16<<<dim3(512), dim3(256), 0, stream>>>(wo, wo_b, (int)(n_w / 4));

    dim3 gg(NB * S_LEN / BM, D_MODEL / BN);  // (32, 16)
    gemm_bt<unsigned short><<<gg, 256, 0, stream>>>(inp_b, wq_b, Qb, NB * S_LEN, D_MODEL, D_MODEL);
    gemm_bt<unsigned short><<<gg, 256, 0, stream>>>(inp_b, wk_b, Kb, NB * S_LEN, D_MODEL, D_MODEL);
    gemm_bt<unsigned short><<<gg, 256, 0, stream>>>(inp_b, wv_b, Vb, NB * S_LEN, D_MODEL, D_MODEL);

    flash_attn<<<dim3(S_LEN / 64, NH, NB), 256, 0, stream>>>(Qb, Kb, Vb, bias, softcap, Ob);

    gemm_bt<float><<<gg, 256, 0, stream>>>(Ob, wo_b, out, NB * S_LEN, D_MODEL, D_MODEL);
}